// Round 1
// baseline (1647.252 us; speedup 1.0000x reference)
//
#include <hip/hip_runtime.h>
#include <math.h>

#define N_NODES 50000
#define N_EDGES 1600000

// ---------- preprocessing ----------
__global__ void k_deg(const int* __restrict__ src, const float* __restrict__ w,
                      float* __restrict__ deg, int n) {
    int i = blockIdx.x * blockDim.x + threadIdx.x;
    if (i < n) atomicAdd(&deg[src[i]], w[i]);
}

__global__ void k_dinv(float* deg, int n) {
    int i = blockIdx.x * blockDim.x + threadIdx.x;
    if (i < n) {
        float d = deg[i];
        deg[i] = d > 0.f ? rsqrtf(fmaxf(d, 1e-30f)) : 0.f;
    }
}

__global__ void k_norm_count(const int* __restrict__ src, const int* __restrict__ dst,
                             const float* __restrict__ w, const float* __restrict__ dinv,
                             float* __restrict__ norm, int* __restrict__ counts, int n) {
    int i = blockIdx.x * blockDim.x + threadIdx.x;
    if (i < n) {
        norm[i] = -dinv[src[i]] * w[i] * dinv[dst[i]];
        atomicAdd(&counts[dst[i]], 1);
    }
}

// exclusive scan of counts -> row_start (single block, 256 threads)
__global__ void k_scan(const int* __restrict__ counts, int* __restrict__ row_start, int n) {
    __shared__ int strip[256];
    int tid = threadIdx.x;
    int per = (n + 255) / 256;
    int b = tid * per;
    int e = min(b + per, n);
    int s = 0;
    for (int i = b; i < e; i++) s += counts[i];
    strip[tid] = s;
    __syncthreads();
    if (tid == 0) {
        int acc = 0;
        for (int i = 0; i < 256; i++) { int v = strip[i]; strip[i] = acc; acc += v; }
    }
    __syncthreads();
    int off = strip[tid];
    for (int i = b; i < e; i++) { row_start[i] = off; off += counts[i]; }
    if (tid == 255) row_start[n] = off;
}

__global__ void k_scatter(const int* __restrict__ src, const int* __restrict__ dst,
                          const float* __restrict__ norm, const int* __restrict__ row_start,
                          int* __restrict__ cursor, int* __restrict__ csr_src,
                          float* __restrict__ csr_norm, int n) {
    int i = blockIdx.x * blockDim.x + threadIdx.x;
    if (i < n) {
        int d = dst[i];
        int p = row_start[d] + atomicAdd(&cursor[d], 1);
        csr_src[p] = src[i];
        csr_norm[p] = norm[i];
    }
}

// copy x (50000x128) into T slice 0 (row stride 384)
__global__ void k_copy_x(const float* __restrict__ x, float* __restrict__ T, int n4) {
    int i = blockIdx.x * blockDim.x + threadIdx.x;  // float4 index
    if (i < n4) {
        int node = i >> 5;
        int c4 = (i & 31) << 2;
        *(float4*)&T[node * 384 + c4] = *(const float4*)&x[node * 128 + c4];
    }
}

// ---------- SpMM: one wave per node, lane owns 2 features ----------
// out[node, out_off + f] = (mode ? 2*acc - T[node, f] : acc)
// acc = sum over CSR row of norm[e] * T[src[e], in_off + f]
__global__ __launch_bounds__(256) void k_spmm(float* T, const int* __restrict__ row_start,
                                              const int* __restrict__ csr_src,
                                              const float* __restrict__ csr_norm,
                                              int in_off, int out_off, int mode) {
    int node = blockIdx.x * 4 + (threadIdx.x >> 6);
    int lane = threadIdx.x & 63;
    int s = row_start[node];
    int e = row_start[node + 1];
    float ax = 0.f, ay = 0.f;
    for (int j = s; j < e; j++) {
        int sp = csr_src[j];
        float nv = csr_norm[j];
        const float2 xr = *(const float2*)&T[(size_t)sp * 384 + in_off + 2 * lane];
        ax = fmaf(nv, xr.x, ax);
        ay = fmaf(nv, xr.y, ay);
    }
    float ox = ax, oy = ay;
    if (mode) {
        const float2 t0 = *(const float2*)&T[(size_t)node * 384 + 2 * lane];
        ox = 2.f * ax - t0.x;
        oy = 2.f * ay - t0.y;
    }
    float2 o; o.x = ox; o.y = oy;
    *(float2*)&T[(size_t)node * 384 + out_off + 2 * lane] = o;
}

// ---------- fused GEMM: H = sigmoid(A[Mx384] @ W[384xC] + b) ----------
// A and out may alias (out = slice 0 of T): per-row tile is owned by exactly
// one block, and all A reads complete before the epilogue stores. NO __restrict__
// on A/out for that reason.
template <int C>
__global__ __launch_bounds__(256) void k_gemm(const float* A, const float* __restrict__ W,
                                              const float* __restrict__ bias, float* out,
                                              int out_stride, int M) {
    constexpr int BM = 64, BK = 32, TN = C / 16;
    __shared__ float As[BM][BK + 1];
    __shared__ float Bs[BK][C];
    int tid = threadIdx.x;
    int m0 = blockIdx.x * BM;
    int ty = tid >> 4, tx = tid & 15;  // 16x16 thread tile
    float acc[4][TN];
    for (int r = 0; r < 4; r++)
        for (int c = 0; c < TN; c++) acc[r][c] = 0.f;

    for (int k0 = 0; k0 < 384; k0 += BK) {
        // A tile: 64x32 floats = 512 float4, 2 per thread
        for (int i = 0; i < 2; i++) {
            int idx = tid * 2 + i;
            int r = idx >> 3;
            int c4 = (idx & 7) * 4;
            float4 v = make_float4(0.f, 0.f, 0.f, 0.f);
            if (m0 + r < M) v = *(const float4*)&A[(size_t)(m0 + r) * 384 + k0 + c4];
            As[r][c4 + 0] = v.x; As[r][c4 + 1] = v.y;
            As[r][c4 + 2] = v.z; As[r][c4 + 3] = v.w;
        }
        // B tile: 32xC floats
        constexpr int NB4 = BK * C / 4 / 256;
        for (int i = 0; i < NB4; i++) {
            int idx = tid + i * 256;
            int r = idx / (C / 4);
            int c4 = (idx % (C / 4)) * 4;
            *(float4*)&Bs[r][c4] = *(const float4*)&W[(size_t)(k0 + r) * C + c4];
        }
        __syncthreads();
        for (int kk = 0; kk < BK; kk++) {
            float a[4], b[TN];
            for (int r = 0; r < 4; r++) a[r] = As[ty * 4 + r][kk];
            for (int c = 0; c < TN; c++) b[c] = Bs[kk][tx * TN + c];
            for (int r = 0; r < 4; r++)
                for (int c = 0; c < TN; c++) acc[r][c] = fmaf(a[r], b[c], acc[r][c]);
        }
        __syncthreads();
    }
    for (int r = 0; r < 4; r++) {
        int row = m0 + ty * 4 + r;
        if (row < M) {
            for (int c = 0; c < TN; c++) {
                float v = acc[r][c] + bias[tx * TN + c];
                v = 1.f / (1.f + expf(-v));
                out[(size_t)row * out_stride + tx * TN + c] = v;
            }
        }
    }
}

extern "C" void kernel_launch(void* const* d_in, const int* in_sizes, int n_in,
                              void* d_out, int out_size, void* d_ws, size_t ws_size,
                              hipStream_t stream) {
    const float* x  = (const float*)d_in[0];
    const int*   ei = (const int*)d_in[1];
    const float* ew = (const float*)d_in[2];
    const float* W0 = (const float*)d_in[3];
    const float* b0 = (const float*)d_in[4];
    const float* W1 = (const float*)d_in[5];
    const float* b1 = (const float*)d_in[6];
    const float* W2 = (const float*)d_in[7];
    const float* b2 = (const float*)d_in[8];
    const int* src = ei;
    const int* dst = ei + N_EDGES;

    char* ws = (char*)d_ws;
    size_t off = 0;
    auto alloc = [&](size_t bytes) -> char* {
        size_t p = (off + 255) & ~(size_t)255;
        off = p + bytes;
        return ws + p;
    };
    float* T         = (float*)alloc((size_t)N_NODES * 384 * 4);  // [T0|T1|T2] row-major
    float* deg       = (float*)alloc((size_t)N_NODES * 4);        // deg -> dinv in place
    float* norm      = (float*)alloc((size_t)N_EDGES * 4);
    int*   counts    = (int*)alloc((size_t)N_NODES * 4);          // histogram, then cursor
    int*   row_start = (int*)alloc((size_t)(N_NODES + 1) * 4);
    int*   csr_src   = (int*)alloc((size_t)N_EDGES * 4);
    float* csr_norm  = (float*)alloc((size_t)N_EDGES * 4);

    hipMemsetAsync(deg, 0, N_NODES * 4, stream);
    hipMemsetAsync(counts, 0, N_NODES * 4, stream);

    int eb = (N_EDGES + 255) / 256;
    int nb = (N_NODES + 255) / 256;
    k_deg<<<eb, 256, 0, stream>>>(src, ew, deg, N_EDGES);
    k_dinv<<<nb, 256, 0, stream>>>(deg, N_NODES);
    k_norm_count<<<eb, 256, 0, stream>>>(src, dst, ew, deg, norm, counts, N_EDGES);
    k_scan<<<1, 256, 0, stream>>>(counts, row_start, N_NODES);
    hipMemsetAsync(counts, 0, N_NODES * 4, stream);  // reuse as cursor
    k_scatter<<<eb, 256, 0, stream>>>(src, dst, norm, row_start, counts, csr_src, csr_norm, N_EDGES);
    k_copy_x<<<(N_NODES * 32 + 255) / 256, 256, 0, stream>>>(x, T, N_NODES * 32);

    const float* Wl[3] = {W0, W1, W2};
    const float* bl[3] = {b0, b1, b2};
    int gemm_blocks = (N_NODES + 63) / 64;
    for (int l = 0; l < 3; l++) {
        // T1 = L x  (slice0 -> slice1)
        k_spmm<<<N_NODES / 4, 256, 0, stream>>>(T, row_start, csr_src, csr_norm, 0, 128, 0);
        // T2 = 2*L*T1 - T0  (slice1 -> slice2)
        k_spmm<<<N_NODES / 4, 256, 0, stream>>>(T, row_start, csr_src, csr_norm, 128, 256, 1);
        if (l < 2)
            k_gemm<128><<<gemm_blocks, 256, 0, stream>>>(T, Wl[l], bl[l], T, 384, N_NODES);
        else
            k_gemm<64><<<gemm_blocks, 256, 0, stream>>>(T, Wl[l], bl[l], (float*)d_out, 64, N_NODES);
    }
}

// Round 2
// 1356.753 us; speedup vs baseline: 1.2141x; 1.2141x over previous
//
#include <hip/hip_runtime.h>
#include <math.h>

#define N_NODES 50000
#define N_EDGES 1600000

// ---------- preprocessing ----------
__global__ void k_deg(const int* __restrict__ src, const float* __restrict__ w,
                      float* __restrict__ deg, int n) {
    int i = blockIdx.x * blockDim.x + threadIdx.x;
    if (i < n) atomicAdd(&deg[src[i]], w[i]);
}

__global__ void k_dinv(float* deg, int n) {
    int i = blockIdx.x * blockDim.x + threadIdx.x;
    if (i < n) {
        float d = deg[i];
        deg[i] = d > 0.f ? rsqrtf(fmaxf(d, 1e-30f)) : 0.f;
    }
}

__global__ void k_norm_count(const int* __restrict__ src, const int* __restrict__ dst,
                             const float* __restrict__ w, const float* __restrict__ dinv,
                             float* __restrict__ norm, int* __restrict__ counts, int n) {
    int i = blockIdx.x * blockDim.x + threadIdx.x;
    if (i < n) {
        norm[i] = -dinv[src[i]] * w[i] * dinv[dst[i]];
        atomicAdd(&counts[dst[i]], 1);
    }
}

// exclusive scan of counts -> row_start (single block, 256 threads)
__global__ void k_scan(const int* __restrict__ counts, int* __restrict__ row_start, int n) {
    __shared__ int strip[256];
    int tid = threadIdx.x;
    int per = (n + 255) / 256;
    int b = tid * per;
    int e = min(b + per, n);
    int s = 0;
    for (int i = b; i < e; i++) s += counts[i];
    strip[tid] = s;
    __syncthreads();
    if (tid == 0) {
        int acc = 0;
        for (int i = 0; i < 256; i++) { int v = strip[i]; strip[i] = acc; acc += v; }
    }
    __syncthreads();
    int off = strip[tid];
    for (int i = b; i < e; i++) { row_start[i] = off; off += counts[i]; }
    if (tid == 255) row_start[n] = off;
}

__global__ void k_scatter(const int* __restrict__ src, const int* __restrict__ dst,
                          const float* __restrict__ norm, const int* __restrict__ row_start,
                          int* __restrict__ cursor, int* __restrict__ csr_src,
                          float* __restrict__ csr_norm, int n) {
    int i = blockIdx.x * blockDim.x + threadIdx.x;
    if (i < n) {
        int d = dst[i];
        int p = row_start[d] + atomicAdd(&cursor[d], 1);
        csr_src[p] = src[i];
        csr_norm[p] = norm[i];
    }
}

// copy x (50000x128) into T slice 0 (row stride 384)
__global__ void k_copy_x(const float* __restrict__ x, float* __restrict__ T, int n4) {
    int i = blockIdx.x * blockDim.x + threadIdx.x;  // float4 index
    if (i < n4) {
        int node = i >> 5;
        int c4 = (i & 31) << 2;
        *(float4*)&T[node * 384 + c4] = *(const float4*)&x[node * 128 + c4];
    }
}

// ---------- SpMM: one wave per node, lane owns 2 features ----------
// out[node, out_off + f] = (mode ? 2*acc - T[node, f] : acc)
// acc = sum over CSR row of norm[e] * T[src[e], in_off + f]
// Unrolled x8 with independent accumulators: keeps ~8 gathers in flight per
// wave to cover L2/LLC latency (R0 profile: VGPR=12, VALUBusy=11%, 31% HBM ->
// latency-bound with ~1 load in flight).
__global__ __launch_bounds__(256) void k_spmm(float* T, const int* __restrict__ row_start,
                                              const int* __restrict__ csr_src,
                                              const float* __restrict__ csr_norm,
                                              int in_off, int out_off, int mode) {
    int node = blockIdx.x * 4 + (threadIdx.x >> 6);
    int lane = threadIdx.x & 63;
    int s = row_start[node];
    int e = row_start[node + 1];
    const float* Tin = T + in_off + 2 * lane;
    float ax0 = 0.f, ay0 = 0.f, ax1 = 0.f, ay1 = 0.f;
    float ax2 = 0.f, ay2 = 0.f, ax3 = 0.f, ay3 = 0.f;
    float ax4 = 0.f, ay4 = 0.f, ax5 = 0.f, ay5 = 0.f;
    float ax6 = 0.f, ay6 = 0.f, ax7 = 0.f, ay7 = 0.f;
    int j = s;
    for (; j + 8 <= e; j += 8) {
        int sp0 = csr_src[j + 0], sp1 = csr_src[j + 1];
        int sp2 = csr_src[j + 2], sp3 = csr_src[j + 3];
        int sp4 = csr_src[j + 4], sp5 = csr_src[j + 5];
        int sp6 = csr_src[j + 6], sp7 = csr_src[j + 7];
        float n0 = csr_norm[j + 0], n1 = csr_norm[j + 1];
        float n2 = csr_norm[j + 2], n3 = csr_norm[j + 3];
        float n4 = csr_norm[j + 4], n5 = csr_norm[j + 5];
        float n6 = csr_norm[j + 6], n7 = csr_norm[j + 7];
        float2 r0 = *(const float2*)&Tin[(size_t)sp0 * 384];
        float2 r1 = *(const float2*)&Tin[(size_t)sp1 * 384];
        float2 r2 = *(const float2*)&Tin[(size_t)sp2 * 384];
        float2 r3 = *(const float2*)&Tin[(size_t)sp3 * 384];
        float2 r4 = *(const float2*)&Tin[(size_t)sp4 * 384];
        float2 r5 = *(const float2*)&Tin[(size_t)sp5 * 384];
        float2 r6 = *(const float2*)&Tin[(size_t)sp6 * 384];
        float2 r7 = *(const float2*)&Tin[(size_t)sp7 * 384];
        ax0 = fmaf(n0, r0.x, ax0); ay0 = fmaf(n0, r0.y, ay0);
        ax1 = fmaf(n1, r1.x, ax1); ay1 = fmaf(n1, r1.y, ay1);
        ax2 = fmaf(n2, r2.x, ax2); ay2 = fmaf(n2, r2.y, ay2);
        ax3 = fmaf(n3, r3.x, ax3); ay3 = fmaf(n3, r3.y, ay3);
        ax4 = fmaf(n4, r4.x, ax4); ay4 = fmaf(n4, r4.y, ay4);
        ax5 = fmaf(n5, r5.x, ax5); ay5 = fmaf(n5, r5.y, ay5);
        ax6 = fmaf(n6, r6.x, ax6); ay6 = fmaf(n6, r6.y, ay6);
        ax7 = fmaf(n7, r7.x, ax7); ay7 = fmaf(n7, r7.y, ay7);
    }
    for (; j < e; j++) {
        int sp = csr_src[j];
        float nv = csr_norm[j];
        float2 r = *(const float2*)&Tin[(size_t)sp * 384];
        ax0 = fmaf(nv, r.x, ax0); ay0 = fmaf(nv, r.y, ay0);
    }
    float ax = ((ax0 + ax1) + (ax2 + ax3)) + ((ax4 + ax5) + (ax6 + ax7));
    float ay = ((ay0 + ay1) + (ay2 + ay3)) + ((ay4 + ay5) + (ay6 + ay7));
    float ox = ax, oy = ay;
    if (mode) {
        const float2 t0 = *(const float2*)&T[(size_t)node * 384 + 2 * lane];
        ox = 2.f * ax - t0.x;
        oy = 2.f * ay - t0.y;
    }
    float2 o; o.x = ox; o.y = oy;
    *(float2*)&T[(size_t)node * 384 + out_off + 2 * lane] = o;
}

// ---------- fused GEMM: H = sigmoid(A[Mx384] @ W[384xC] + b) ----------
// A and out may alias (out = slice 0 of T): per-row tile is owned by exactly
// one block, and all A reads complete before the epilogue stores. NO __restrict__
// on A/out for that reason.
template <int C>
__global__ __launch_bounds__(256) void k_gemm(const float* A, const float* __restrict__ W,
                                              const float* __restrict__ bias, float* out,
                                              int out_stride, int M) {
    constexpr int BM = 64, BK = 32, TN = C / 16;
    __shared__ float As[BM][BK + 1];
    __shared__ float Bs[BK][C];
    int tid = threadIdx.x;
    int m0 = blockIdx.x * BM;
    int ty = tid >> 4, tx = tid & 15;  // 16x16 thread tile
    float acc[4][TN];
    for (int r = 0; r < 4; r++)
        for (int c = 0; c < TN; c++) acc[r][c] = 0.f;

    for (int k0 = 0; k0 < 384; k0 += BK) {
        // A tile: 64x32 floats = 512 float4, 2 per thread
        for (int i = 0; i < 2; i++) {
            int idx = tid * 2 + i;
            int r = idx >> 3;
            int c4 = (idx & 7) * 4;
            float4 v = make_float4(0.f, 0.f, 0.f, 0.f);
            if (m0 + r < M) v = *(const float4*)&A[(size_t)(m0 + r) * 384 + k0 + c4];
            As[r][c4 + 0] = v.x; As[r][c4 + 1] = v.y;
            As[r][c4 + 2] = v.z; As[r][c4 + 3] = v.w;
        }
        // B tile: 32xC floats
        constexpr int NB4 = BK * C / 4 / 256;
        for (int i = 0; i < NB4; i++) {
            int idx = tid + i * 256;
            int r = idx / (C / 4);
            int c4 = (idx % (C / 4)) * 4;
            *(float4*)&Bs[r][c4] = *(const float4*)&W[(size_t)(k0 + r) * C + c4];
        }
        __syncthreads();
        for (int kk = 0; kk < BK; kk++) {
            float a[4], b[TN];
            for (int r = 0; r < 4; r++) a[r] = As[ty * 4 + r][kk];
            for (int c = 0; c < TN; c++) b[c] = Bs[kk][tx * TN + c];
            for (int r = 0; r < 4; r++)
                for (int c = 0; c < TN; c++) acc[r][c] = fmaf(a[r], b[c], acc[r][c]);
        }
        __syncthreads();
    }
    for (int r = 0; r < 4; r++) {
        int row = m0 + ty * 4 + r;
        if (row < M) {
            for (int c = 0; c < TN; c++) {
                float v = acc[r][c] + bias[tx * TN + c];
                v = 1.f / (1.f + expf(-v));
                out[(size_t)row * out_stride + tx * TN + c] = v;
            }
        }
    }
}

extern "C" void kernel_launch(void* const* d_in, const int* in_sizes, int n_in,
                              void* d_out, int out_size, void* d_ws, size_t ws_size,
                              hipStream_t stream) {
    const float* x  = (const float*)d_in[0];
    const int*   ei = (const int*)d_in[1];
    const float* ew = (const float*)d_in[2];
    const float* W0 = (const float*)d_in[3];
    const float* b0 = (const float*)d_in[4];
    const float* W1 = (const float*)d_in[5];
    const float* b1 = (const float*)d_in[6];
    const float* W2 = (const float*)d_in[7];
    const float* b2 = (const float*)d_in[8];
    const int* src = ei;
    const int* dst = ei + N_EDGES;

    char* ws = (char*)d_ws;
    size_t off = 0;
    auto alloc = [&](size_t bytes) -> char* {
        size_t p = (off + 255) & ~(size_t)255;
        off = p + bytes;
        return ws + p;
    };
    float* T         = (float*)alloc((size_t)N_NODES * 384 * 4);  // [T0|T1|T2] row-major
    float* deg       = (float*)alloc((size_t)N_NODES * 4);        // deg -> dinv in place
    float* norm      = (float*)alloc((size_t)N_EDGES * 4);
    int*   counts    = (int*)alloc((size_t)N_NODES * 4);          // histogram, then cursor
    int*   row_start = (int*)alloc((size_t)(N_NODES + 1) * 4);
    int*   csr_src   = (int*)alloc((size_t)N_EDGES * 4);
    float* csr_norm  = (float*)alloc((size_t)N_EDGES * 4);

    hipMemsetAsync(deg, 0, N_NODES * 4, stream);
    hipMemsetAsync(counts, 0, N_NODES * 4, stream);

    int eb = (N_EDGES + 255) / 256;
    int nb = (N_NODES + 255) / 256;
    k_deg<<<eb, 256, 0, stream>>>(src, ew, deg, N_EDGES);
    k_dinv<<<nb, 256, 0, stream>>>(deg, N_NODES);
    k_norm_count<<<eb, 256, 0, stream>>>(src, dst, ew, deg, norm, counts, N_EDGES);
    k_scan<<<1, 256, 0, stream>>>(counts, row_start, N_NODES);
    hipMemsetAsync(counts, 0, N_NODES * 4, stream);  // reuse as cursor
    k_scatter<<<eb, 256, 0, stream>>>(src, dst, norm, row_start, counts, csr_src, csr_norm, N_EDGES);
    k_copy_x<<<(N_NODES * 32 + 255) / 256, 256, 0, stream>>>(x, T, N_NODES * 32);

    const float* Wl[3] = {W0, W1, W2};
    const float* bl[3] = {b0, b1, b2};
    int gemm_blocks = (N_NODES + 63) / 64;
    for (int l = 0; l < 3; l++) {
        // T1 = L x  (slice0 -> slice1)
        k_spmm<<<N_NODES / 4, 256, 0, stream>>>(T, row_start, csr_src, csr_norm, 0, 128, 0);
        // T2 = 2*L*T1 - T0  (slice1 -> slice2)
        k_spmm<<<N_NODES / 4, 256, 0, stream>>>(T, row_start, csr_src, csr_norm, 128, 256, 1);
        if (l < 2)
            k_gemm<128><<<gemm_blocks, 256, 0, stream>>>(T, Wl[l], bl[l], T, 384, N_NODES);
        else
            k_gemm<64><<<gemm_blocks, 256, 0, stream>>>(T, Wl[l], bl[l], (float*)d_out, 64, N_NODES);
    }
}

// Round 3
// 741.204 us; speedup vs baseline: 2.2224x; 1.8305x over previous
//
#include <hip/hip_runtime.h>
#include <hip/hip_fp16.h>
#include <math.h>

#define N_NODES 50000
#define N_EDGES 1600000
#define NB_NODES ((N_NODES + 255) / 256)   // 196

typedef _Float16 f16x8 __attribute__((ext_vector_type(8)));
typedef float f32x4 __attribute__((ext_vector_type(4)));

// ---------- preprocessing ----------
// fused: deg[src] += w  and  counts[dst] += 1
__global__ void k_deg_count(const int* __restrict__ src, const int* __restrict__ dst,
                            const float* __restrict__ w, float* __restrict__ deg,
                            int* __restrict__ counts, int n) {
    int i = blockIdx.x * blockDim.x + threadIdx.x;
    if (i < n) {
        atomicAdd(&deg[src[i]], w[i]);
        atomicAdd(&counts[dst[i]], 1);
    }
}

__global__ void k_dinv(float* deg, int n) {
    int i = blockIdx.x * blockDim.x + threadIdx.x;
    if (i < n) {
        float d = deg[i];
        deg[i] = d > 0.f ? rsqrtf(fmaxf(d, 1e-30f)) : 0.f;
    }
}

// hierarchical exclusive scan: scan1 (per-block) -> scan2 (block sums) -> scan3 (add)
__global__ void k_scan1(const int* __restrict__ counts, int* __restrict__ row_start,
                        int* __restrict__ bsum, int n) {
    __shared__ int s[256];
    int tid = threadIdx.x;
    int i = blockIdx.x * 256 + tid;
    int v = (i < n) ? counts[i] : 0;
    s[tid] = v;
    __syncthreads();
    for (int off = 1; off < 256; off <<= 1) {
        int t = (tid >= off) ? s[tid - off] : 0;
        __syncthreads();
        s[tid] += t;
        __syncthreads();
    }
    if (i < n) row_start[i] = s[tid] - v;  // exclusive within block
    if (tid == 255) bsum[blockIdx.x] = s[255];
}

__global__ void k_scan2(int* bsum, int nb) {  // single block, nb <= 256
    __shared__ int s[256];
    int tid = threadIdx.x;
    int v = (tid < nb) ? bsum[tid] : 0;
    s[tid] = v;
    __syncthreads();
    for (int off = 1; off < 256; off <<= 1) {
        int t = (tid >= off) ? s[tid - off] : 0;
        __syncthreads();
        s[tid] += t;
        __syncthreads();
    }
    if (tid < nb) bsum[tid] = s[tid] - v;  // exclusive
}

__global__ void k_scan3(int* __restrict__ row_start, const int* __restrict__ bsum, int n) {
    int i = blockIdx.x * 256 + threadIdx.x;
    if (i < n) row_start[i] += bsum[i >> 8];
    if (i == 0) row_start[n] = N_EDGES;
}

// fused scatter: computes norm inline, packs (src, norm) into one 8B store
// (R1 profile: two 4B random stores/edge -> WRITE_SIZE 145MB, 11x amplification)
__global__ void k_scatter(const int* __restrict__ src, const int* __restrict__ dst,
                          const float* __restrict__ w, const float* __restrict__ dinv,
                          const int* __restrict__ row_start, int* __restrict__ cursor,
                          uint2* __restrict__ csr, int n) {
    int i = blockIdx.x * blockDim.x + threadIdx.x;
    if (i < n) {
        int s = src[i], d = dst[i];
        float nv = -dinv[s] * w[i] * dinv[d];
        int p = row_start[d] + atomicAdd(&cursor[d], 1);
        uint2 r;
        r.x = (unsigned)s;
        r.y = __float_as_uint(nv);
        csr[p] = r;
    }
}

// copy x (50000x128 fp32) into Th slice 0 (f16, row stride 384)
__global__ void k_copy_x(const float* __restrict__ x, __half* __restrict__ Th, int n2) {
    int i = blockIdx.x * blockDim.x + threadIdx.x;  // half2 index
    if (i < n2) {
        int node = i >> 6;
        int c2 = (i & 63) * 2;
        float2 v = *(const float2*)&x[(size_t)node * 128 + c2];
        *(__half2*)&Th[(size_t)node * 384 + c2] = __floats2half2_rn(v.x, v.y);
    }
}

// W (384 x C fp32, k = kcheb*128 + cin) -> Wt (C x 384 f16), Wt[n*384+k] = W[k*C+n]
__global__ void k_wt(const float* __restrict__ W, __half* __restrict__ Wt, int C) {
    int i = blockIdx.x * blockDim.x + threadIdx.x;
    if (i < C * 384) {
        int n = i / 384, k = i % 384;
        Wt[i] = __float2half(W[(size_t)k * C + n]);
    }
}

// ---------- SpMM: one wave per node, lane owns 2 f16 features ----------
// out[node, out_off+f] = mode ? 2*acc - Th[node, f] : acc
// unrolled x8 (independent gathers in flight to cover L2/LLC latency)
__global__ __launch_bounds__(256) void k_spmm(__half* Th, const int* __restrict__ row_start,
                                              const uint2* __restrict__ csr,
                                              int in_off, int out_off, int mode) {
    int node = blockIdx.x * 4 + (threadIdx.x >> 6);
    int lane = threadIdx.x & 63;
    int s = row_start[node];
    int e = row_start[node + 1];
    const __half* Tin = Th + in_off + 2 * lane;
    float ax0 = 0.f, ay0 = 0.f, ax1 = 0.f, ay1 = 0.f;
    float ax2 = 0.f, ay2 = 0.f, ax3 = 0.f, ay3 = 0.f;
    float ax4 = 0.f, ay4 = 0.f, ax5 = 0.f, ay5 = 0.f;
    float ax6 = 0.f, ay6 = 0.f, ax7 = 0.f, ay7 = 0.f;
    int j = s;
    for (; j + 8 <= e; j += 8) {
        uint2 e0 = csr[j + 0], e1 = csr[j + 1], e2 = csr[j + 2], e3 = csr[j + 3];
        uint2 e4 = csr[j + 4], e5 = csr[j + 5], e6 = csr[j + 6], e7 = csr[j + 7];
        __half2 r0 = *(const __half2*)&Tin[(size_t)e0.x * 384];
        __half2 r1 = *(const __half2*)&Tin[(size_t)e1.x * 384];
        __half2 r2 = *(const __half2*)&Tin[(size_t)e2.x * 384];
        __half2 r3 = *(const __half2*)&Tin[(size_t)e3.x * 384];
        __half2 r4 = *(const __half2*)&Tin[(size_t)e4.x * 384];
        __half2 r5 = *(const __half2*)&Tin[(size_t)e5.x * 384];
        __half2 r6 = *(const __half2*)&Tin[(size_t)e6.x * 384];
        __half2 r7 = *(const __half2*)&Tin[(size_t)e7.x * 384];
        float2 f0 = __half22float2(r0), f1 = __half22float2(r1);
        float2 f2 = __half22float2(r2), f3 = __half22float2(r3);
        float2 f4 = __half22float2(r4), f5 = __half22float2(r5);
        float2 f6 = __half22float2(r6), f7 = __half22float2(r7);
        float n0 = __uint_as_float(e0.y), n1 = __uint_as_float(e1.y);
        float n2 = __uint_as_float(e2.y), n3 = __uint_as_float(e3.y);
        float n4 = __uint_as_float(e4.y), n5 = __uint_as_float(e5.y);
        float n6 = __uint_as_float(e6.y), n7 = __uint_as_float(e7.y);
        ax0 = fmaf(n0, f0.x, ax0); ay0 = fmaf(n0, f0.y, ay0);
        ax1 = fmaf(n1, f1.x, ax1); ay1 = fmaf(n1, f1.y, ay1);
        ax2 = fmaf(n2, f2.x, ax2); ay2 = fmaf(n2, f2.y, ay2);
        ax3 = fmaf(n3, f3.x, ax3); ay3 = fmaf(n3, f3.y, ay3);
        ax4 = fmaf(n4, f4.x, ax4); ay4 = fmaf(n4, f4.y, ay4);
        ax5 = fmaf(n5, f5.x, ax5); ay5 = fmaf(n5, f5.y, ay5);
        ax6 = fmaf(n6, f6.x, ax6); ay6 = fmaf(n6, f6.y, ay6);
        ax7 = fmaf(n7, f7.x, ax7); ay7 = fmaf(n7, f7.y, ay7);
    }
    for (; j < e; j++) {
        uint2 ee = csr[j];
        __half2 r = *(const __half2*)&Tin[(size_t)ee.x * 384];
        float2 f = __half22float2(r);
        float nv = __uint_as_float(ee.y);
        ax0 = fmaf(nv, f.x, ax0); ay0 = fmaf(nv, f.y, ay0);
    }
    float ax = ((ax0 + ax1) + (ax2 + ax3)) + ((ax4 + ax5) + (ax6 + ax7));
    float ay = ((ay0 + ay1) + (ay2 + ay3)) + ((ay4 + ay5) + (ay6 + ay7));
    float ox = ax, oy = ay;
    if (mode) {
        __half2 t0h = *(const __half2*)&Th[(size_t)node * 384 + 2 * lane];
        float2 t0 = __half22float2(t0h);
        ox = 2.f * ax - t0.x;
        oy = 2.f * ay - t0.y;
    }
    *(__half2*)&Th[(size_t)node * 384 + out_off + 2 * lane] = __floats2half2_rn(ox, oy);
}

// ---------- MFMA GEMM: out = sigmoid(A[Mx384 f16] @ Wt^T[384xC f16] + b) ----------
// Block: 256 thr = 4 waves; block tile 64(M) x C(N); wave tile 16 x C.
// mfma_f32_16x16x32_f16: A[m=lane&15][k=(lane>>4)*8+j]; C/D col=lane&15,row=(lane>>4)*4+r.
// mode 0: write f16 to Th slice0 (stride 384); mode 1: write fp32 (stride C).
// A and out may alias (rows owned exclusively per block; reads all complete
// before epilogue stores) -> no __restrict__ on A/out.
template <int C>
__global__ __launch_bounds__(256) void k_gemm(const __half* A, const __half* __restrict__ Wt,
                                              const float* __restrict__ bias, void* out,
                                              int mode, int M) {
    constexpr int NF = C / 16;
    __shared__ _Float16 As[64][56];   // pad 32->56 f16: 16B-aligned rows, 2-way banks
    __shared__ _Float16 Bs[C][56];
    int tid = threadIdx.x;
    int wave = tid >> 6, lane = tid & 63;
    int lm = lane & 15, lq = lane >> 4;
    int m0 = blockIdx.x * 64;
    f32x4 acc[NF];
    for (int nf = 0; nf < NF; nf++) acc[nf] = (f32x4)0.0f;

    for (int k0 = 0; k0 < 384; k0 += 32) {
        {   // A tile: 64 rows x 32 f16 = 256 x 16B chunks, 1/thread
            int r = tid >> 2, q = tid & 3;
            int row = m0 + r;
            if (row >= M) row = M - 1;  // clamp; stores are guarded
            *(f16x8*)&As[r][q * 8] = *(const f16x8*)&A[(size_t)row * 384 + k0 + q * 8];
        }
        // B tile: C rows x 32 f16
        for (int i = 0; i < (C * 4) / 256; i++) {
            int idx = tid + i * 256;
            int n = idx >> 2, q = idx & 3;
            *(f16x8*)&Bs[n][q * 8] = *(const f16x8*)&Wt[(size_t)n * 384 + k0 + q * 8];
        }
        __syncthreads();
        f16x8 a = *(const f16x8*)&As[wave * 16 + lm][lq * 8];
        for (int nf = 0; nf < NF; nf++) {
            f16x8 b = *(const f16x8*)&Bs[nf * 16 + lm][lq * 8];
            acc[nf] = __builtin_amdgcn_mfma_f32_16x16x32_f16(a, b, acc[nf], 0, 0, 0);
        }
        __syncthreads();
    }
    for (int nf = 0; nf < NF; nf++) {
        for (int r = 0; r < 4; r++) {
            int grow = m0 + wave * 16 + lq * 4 + r;
            int col = nf * 16 + lm;
            if (grow < M) {
                float v = acc[nf][r] + bias[col];
                v = 1.f / (1.f + expf(-v));
                if (mode == 0)
                    ((__half*)out)[(size_t)grow * 384 + col] = __float2half(v);
                else
                    ((float*)out)[(size_t)grow * C + col] = v;
            }
        }
    }
}

extern "C" void kernel_launch(void* const* d_in, const int* in_sizes, int n_in,
                              void* d_out, int out_size, void* d_ws, size_t ws_size,
                              hipStream_t stream) {
    const float* x  = (const float*)d_in[0];
    const int*   ei = (const int*)d_in[1];
    const float* ew = (const float*)d_in[2];
    const float* W0 = (const float*)d_in[3];
    const float* b0 = (const float*)d_in[4];
    const float* W1 = (const float*)d_in[5];
    const float* b1 = (const float*)d_in[6];
    const float* W2 = (const float*)d_in[7];
    const float* b2 = (const float*)d_in[8];
    const int* src = ei;
    const int* dst = ei + N_EDGES;

    char* ws = (char*)d_ws;
    size_t off = 0;
    auto alloc = [&](size_t bytes) -> char* {
        size_t p = (off + 255) & ~(size_t)255;
        off = p + bytes;
        return ws + p;
    };
    __half* Th       = (__half*)alloc((size_t)N_NODES * 384 * 2);  // [T0|T1|T2] f16
    float*  deg      = (float*)alloc((size_t)N_NODES * 4);
    int*    counts   = (int*)alloc((size_t)N_NODES * 4);           // histogram, then cursor
    int*    row_start= (int*)alloc((size_t)(N_NODES + 1) * 4);
    int*    bsum     = (int*)alloc(256 * 4);
    uint2*  csr      = (uint2*)alloc((size_t)N_EDGES * 8);         // packed (src, norm)
    __half* Wt0      = (__half*)alloc((size_t)128 * 384 * 2);
    __half* Wt1      = (__half*)alloc((size_t)128 * 384 * 2);
    __half* Wt2      = (__half*)alloc((size_t)64 * 384 * 2);

    hipMemsetAsync(deg, 0, N_NODES * 4, stream);
    hipMemsetAsync(counts, 0, N_NODES * 4, stream);

    int eb = (N_EDGES + 255) / 256;
    k_deg_count<<<eb, 256, 0, stream>>>(src, dst, ew, deg, counts, N_EDGES);
    k_dinv<<<NB_NODES, 256, 0, stream>>>(deg, N_NODES);
    k_scan1<<<NB_NODES, 256, 0, stream>>>(counts, row_start, bsum, N_NODES);
    k_scan2<<<1, 256, 0, stream>>>(bsum, NB_NODES);
    k_scan3<<<NB_NODES, 256, 0, stream>>>(row_start, bsum, N_NODES);
    hipMemsetAsync(counts, 0, N_NODES * 4, stream);  // reuse as cursor
    k_scatter<<<eb, 256, 0, stream>>>(src, dst, ew, deg, row_start, counts, csr, N_EDGES);
    k_copy_x<<<(N_NODES * 64 + 255) / 256, 256, 0, stream>>>(x, Th, N_NODES * 64);
    k_wt<<<(128 * 384 + 255) / 256, 256, 0, stream>>>(W0, Wt0, 128);
    k_wt<<<(128 * 384 + 255) / 256, 256, 0, stream>>>(W1, Wt1, 128);
    k_wt<<<(64 * 384 + 255) / 256, 256, 0, stream>>>(W2, Wt2, 64);

    const __half* Wl[3] = {Wt0, Wt1, Wt2};
    const float*  bl[3] = {b0, b1, b2};
    int gemm_blocks = (N_NODES + 63) / 64;
    for (int l = 0; l < 3; l++) {
        k_spmm<<<N_NODES / 4, 256, 0, stream>>>(Th, row_start, csr, 0, 128, 0);
        k_spmm<<<N_NODES / 4, 256, 0, stream>>>(Th, row_start, csr, 128, 256, 1);
        if (l < 2)
            k_gemm<128><<<gemm_blocks, 256, 0, stream>>>(Th, Wl[l], bl[l], Th, 0, N_NODES);
        else
            k_gemm<64><<<gemm_blocks, 256, 0, stream>>>(Th, Wl[l], bl[l], d_out, 1, N_NODES);
    }
}